// Round 9
// baseline (537.348 us; speedup 1.0000x reference)
//
#include <hip/hip_runtime.h>
#include <math.h>

#define BB 16
#define HH 512
#define WW 512
#define HWP (HH*WW)
#define NPIX (BB*HWP)
#define NCORN 500
#define NSLOT 4096       // 64x64 tiles of 8x8 per image
#define OCAP 1024        // overflow for exact ties with block max (rare)
#define NKEY (NSLOT+OCAP)
#define NKPT (NKEY/256)  // keys per thread in k_selpost = 20
#define NBL 2048         // k_loss blocks

// LDS float offsets for k_front's overlap-reused flat buffer (9164 floats = 36.7KB)
#define GT  0            // gray tile 24x72        [stage A..B]
#define PAo 1728         // products 22x70 x3     [stage B..C]
#define PCo 3268
#define PDo 4808         // end 6348
#define HAo 0            // h-blur 22x64 x3       [stage C..D]  (HA reuses GT)
#define HCo 6348
#define HDo 7756         // end 9164
#define FBUF 9164

__device__ __constant__ float G7c[7] = {
    0.0044330482f, 0.0540055826f, 0.2420362294f, 0.3990502793f,
    0.2420362294f, 0.0540055826f, 0.0044330482f};

__device__ __forceinline__ int reflect_idx(int i, int n) {
    if (i < 0) i = -i;
    if (i >= n) i = 2 * n - 2 - i;
    return i;
}

// 1D scatter weight for reflect-padded 7-tap gaussian blur
__device__ __forceinline__ float w1d(int p, int o, int n) {
    float w = 0.f;
    int d = p - o;
    if (d >= -3 && d <= 3) w += G7c[d + 3];
    if (p >= 1 && p + o <= 3) w += G7c[3 - p - o];
    if (p <= n - 2 && p + o >= 2 * n - 5) w += G7c[2 * n + 1 - p - o];
    return w;
}

// 1) fused gray + sobel(replicate) + H/V 7-tap gaussian + min-eig -> S
//    64x16 tile per 256-thread block; shift-only thread maps; LDS reuse.
__global__ __launch_bounds__(256) void k_front(const float* __restrict__ imgs,
                                               float* __restrict__ S) {
    __shared__ float B[FBUF];
    int x0 = blockIdx.x * 64, y0 = blockIdx.y * 16, b = blockIdx.z;
    const float* ib = imgs + (size_t)b * 3 * HWP;
    int tid = threadIdx.x;
    int r0 = tid >> 6, c0 = tid & 63;

    // A: gray staging 24x72 (clamped -> sobel replicate is automatic)
    for (int rr = r0; rr < 24; rr += 4) {
        int gy = min(max(y0 - 4 + rr, 0), HH - 1);
        const float* rowp = ib + (size_t)gy * WW;
        {
            int gx = min(max(x0 - 4 + c0, 0), WW - 1);
            float R = rowp[gx], G = rowp[HWP + gx], Bl = rowp[2 * HWP + gx];
            B[GT + rr * 72 + c0] = 0.299f * R + 0.587f * G + 0.114f * Bl;
        }
        if (c0 < 8) {
            int c = c0 + 64;
            int gx = min(max(x0 - 4 + c, 0), WW - 1);
            float R = rowp[gx], G = rowp[HWP + gx], Bl = rowp[2 * HWP + gx];
            B[GT + rr * 72 + c] = 0.299f * R + 0.587f * G + 0.114f * Bl;
        }
    }
    __syncthreads();

    // B: sobel products 22x70 (garbage at out-of-image positions: never read)
    for (int rr = r0; rr < 22; rr += 4) {
#pragma unroll
        for (int half = 0; half < 2; ++half) {
            int cc = c0 + half * 64;
            if (half == 1 && c0 >= 6) break;
            int base = GT + rr * 72 + cc;
            float g00 = B[base],       g01 = B[base + 1],   g02 = B[base + 2];
            float g10 = B[base + 72],                        g12 = B[base + 74];
            float g20 = B[base + 144], g21 = B[base + 145], g22 = B[base + 146];
            float dx = (g02 - g00 + 2.f * (g12 - g10) + g22 - g20) * 0.125f;
            float dy = (g20 - g00 + 2.f * (g21 - g01) + g22 - g02) * 0.125f;
            int po = rr * 70 + cc;
            B[PAo + po] = dx * dx;
            B[PCo + po] = dy * dy;
            B[PDo + po] = dx * dy;
        }
    }
    __syncthreads();

    // C: horizontal 7-tap blur -> 22x64 (reflect only on x-edge blocks)
    bool ex = (x0 == 0) || (x0 == WW - 64);
    for (int rr = r0; rr < 22; rr += 4) {
        float A = 0.f, C = 0.f, D = 0.f;
        if (!ex) {
            int base = rr * 70 + c0;
#pragma unroll
            for (int t = 0; t < 7; ++t) {
                float w = G7c[t];
                A += w * B[PAo + base + t];
                C += w * B[PCo + base + t];
                D += w * B[PDo + base + t];
            }
        } else {
#pragma unroll
            for (int t = 0; t < 7; ++t) {
                int px = reflect_idx(x0 + c0 - 3 + t, WW);
                int lc = rr * 70 + (px - (x0 - 3));
                float w = G7c[t];
                A += w * B[PAo + lc];
                C += w * B[PCo + lc];
                D += w * B[PDo + lc];
            }
        }
        int ho = rr * 64 + c0;
        B[HAo + ho] = A; B[HCo + ho] = C; B[HDo + ho] = D;
    }
    __syncthreads();

    // D: vertical 7-tap blur + min-eigenvalue -> S (16x64)
    bool ey = (y0 == 0) || (y0 == HH - 16);
    for (int rr = r0; rr < 16; rr += 4) {
        float A = 0.f, C = 0.f, D = 0.f;
        if (!ey) {
#pragma unroll
            for (int t = 0; t < 7; ++t) {
                int lo = (rr + t) * 64 + c0;
                float w = G7c[t];
                A += w * B[HAo + lo];
                C += w * B[HCo + lo];
                D += w * B[HDo + lo];
            }
        } else {
#pragma unroll
            for (int t = 0; t < 7; ++t) {
                int py = reflect_idx(y0 + rr - 3 + t, HH);
                int lo = (py - (y0 - 3)) * 64 + c0;
                float w = G7c[t];
                A += w * B[HAo + lo];
                C += w * B[HCo + lo];
                D += w * B[HDo + lo];
            }
        }
        float det = A * C - D * D;
        float tr = A + C;
        S[(size_t)b * HWP + (size_t)(y0 + rr) * WW + x0 + c0] =
            0.5f * (tr - sqrtf(fabsf(tr * tr - 4.f * det)));
    }
}

// 2) per-wave 12x12 S tile (stride-16 LDS) -> 5x5 NMS + 8x8-tile max -> slot
__global__ void k_cand2(const float* __restrict__ S, float* __restrict__ sval,
                        int* __restrict__ sidx, int* __restrict__ ocnt) {
    __shared__ float tile[4][12][16];
    int wave = threadIdx.x >> 6, lane = threadIdx.x & 63;
    int tx = blockIdx.x * 4 + wave;
    int ty = blockIdx.y;
    int b = blockIdx.z;
    const float* sb = S + (size_t)b * HWP;
#pragma unroll
    for (int t = 0; t < 3; ++t) {
        int e = lane + t * 64;
        int r = e >> 4, c = e & 15;
        if (c < 12) {
            int yy = min(max(ty * 8 - 2 + r, 0), HH - 1);
            int xx = min(max(tx * 8 - 2 + c, 0), WW - 1);
            tile[wave][r][c] = sb[yy * WW + xx];
        }
    }
    __syncthreads();
    int ly = lane >> 3, lx = lane & 7;
    float v = tile[wave][ly + 2][lx + 2];
    float m = -INFINITY;
#pragma unroll
    for (int dy = 0; dy < 5; ++dy)
#pragma unroll
        for (int dx = 0; dx < 5; ++dx)
            m = fmaxf(m, tile[wave][ly + dy][lx + dx]);
    float cval = (v == m) ? v : 0.f;
    int y = ty * 8 + ly, x = tx * 8 + lx;
    float tm = cval;
#pragma unroll
    for (int off = 32; off; off >>= 1)
        tm = fmaxf(tm, __shfl_xor(tm, off));
    unsigned long long mask = __ballot(cval == tm && cval > 0.f);
    int slot = ty * 64 + tx;
    if (mask) {
        int first = __ffsll(mask) - 1;
        if (lane == first) {
            sval[b * NKEY + slot] = cval;
            sidx[b * NKEY + slot] = y * WW + x;
        } else if ((mask >> lane) & 1ull) {
            int pos = atomicAdd(&ocnt[b], 1);
            if (pos < OCAP) {
                sval[b * NKEY + NSLOT + pos] = cval;
                sidx[b * NKEY + NSLOT + pos] = y * WW + x;
            }
        }
    } else if (lane == 0) {
        sval[b * NKEY + slot] = 0.f;
        sidx[b * NKEY + slot] = 0;
    }
}

// 3) fused: exact 500th key (bit-descent, keys in registers) + sparse NMS +
//    BCE correction C = sum_selected w*(logp - log1mp) -> partialC[b]
__global__ __launch_bounds__(256) void k_selpost(const float* __restrict__ sval,
                       const int* __restrict__ sidx, const int* __restrict__ ocnt,
                       const float* __restrict__ scores,
                       float* __restrict__ partialC) {
    __shared__ int shw[4];
    __shared__ int shtot;
    int b = blockIdx.x;
    int novf = min(ocnt[b], OCAP);
    int n = NSLOT + novf;
    unsigned long long keys[NKPT];
    int cnt = 0;
#pragma unroll
    for (int t = 0; t < NKPT; ++t) {
        int i = threadIdx.x + t * 256;
        unsigned long long k = 0ull;
        if (i < n) {
            float v = sval[b * NKEY + i];
            if (v > 0.f) {
                unsigned int ix = (unsigned int)sidx[b * NKEY + i];
                k = ((unsigned long long)__float_as_uint(v) << 32) |
                    (unsigned long long)(~ix);
                cnt++;
            }
        }
        keys[t] = k;
    }
    int wid = threadIdx.x >> 6;
    {
        int c = cnt;
#pragma unroll
        for (int off = 32; off; off >>= 1) c += __shfl_down(c, off);
        if ((threadIdx.x & 63) == 0) shw[wid] = c;
        __syncthreads();
        if (threadIdx.x == 0) shtot = shw[0] + shw[1] + shw[2] + shw[3];
        __syncthreads();
    }
    int target = min(NCORN, shtot);
    unsigned long long K = 0ull;
    for (int bit = 63; bit >= 0; --bit) {
        unsigned long long cand = K | (1ull << bit);
        int c = 0;
#pragma unroll
        for (int t = 0; t < NKPT; ++t) c += (keys[t] >= cand) ? 1 : 0;
#pragma unroll
        for (int off = 32; off; off >>= 1) c += __shfl_down(c, off);
        __syncthreads();
        if ((threadIdx.x & 63) == 0) shw[wid] = c;
        __syncthreads();
        int tot = shw[0] + shw[1] + shw[2] + shw[3];
        if (tot >= target) K = cand;
    }
    // phase 2: per-candidate sparse NMS + stamp contribution
    const float* bsv = sval + b * NKEY;
    const int* bsi = sidx + b * NKEY;
    const float* sb = scores + (size_t)b * HWP;
    float contrib = 0.f;
#pragma unroll
    for (int t = 0; t < NKPT; ++t) {
        unsigned long long k = keys[t];
        if (k != 0ull && k >= K && target > 0) {
            unsigned int ix = ~(unsigned int)(k & 0xffffffffull);
            float v = __uint_as_float((unsigned int)(k >> 32));
            int y = (int)(ix >> 9), x = (int)(ix & 511);
            bool sup = false;
            int ty0 = max(y - 2, 0) >> 3, ty1 = min(y + 2, HH - 1) >> 3;
            int tx0 = max(x - 2, 0) >> 3, tx1 = min(x + 2, WW - 1) >> 3;
            for (int ty = ty0; ty <= ty1 && !sup; ++ty)
                for (int tx = tx0; tx <= tx1 && !sup; ++tx) {
                    int s2 = ty * 64 + tx;
                    float v2 = bsv[s2];
                    if (v2 <= v) continue;
                    int ix2 = bsi[s2];
                    unsigned long long k2 = ((unsigned long long)__float_as_uint(v2) << 32) |
                                            (unsigned long long)(~(unsigned int)ix2);
                    if (k2 < K) continue;
                    int y2 = ix2 >> 9, x2 = ix2 & 511;
                    if (abs(y2 - y) <= 2 && abs(x2 - x) <= 2) sup = true;
                }
            for (int j = 0; j < novf && !sup; ++j) {
                float v2 = bsv[NSLOT + j];
                if (v2 <= v) continue;
                int ix2 = bsi[NSLOT + j];
                unsigned long long k2 = ((unsigned long long)__float_as_uint(v2) << 32) |
                                        (unsigned long long)(~(unsigned int)ix2);
                if (k2 < K) continue;
                int y2 = ix2 >> 9, x2 = ix2 & 511;
                if (abs(y2 - y) <= 2 && abs(x2 - x) <= 2) sup = true;
            }
            if (!sup) {
                if (y >= 3 && y <= HH - 4 && x >= 3 && x <= WW - 4) {
#pragma unroll
                    for (int j = -3; j <= 3; ++j) {
                        float wy = G7c[j + 3];
#pragma unroll
                        for (int i = -3; i <= 3; ++i) {
                            float w = wy * G7c[i + 3];
                            float p = sb[(y + j) * WW + (x + i)];
                            float lp = fmaxf(__logf(p), -100.f);
                            float l1p = fmaxf(__logf(1.f - p), -100.f);
                            contrib += w * (lp - l1p);
                        }
                    }
                } else {
                    int oy0 = max(y - 6, 0), oy1 = min(y + 6, HH - 1);
                    int ox0 = max(x - 6, 0), ox1 = min(x + 6, WW - 1);
                    for (int oy = oy0; oy <= oy1; ++oy) {
                        float wy = w1d(y, oy, HH);
                        if (wy == 0.f) continue;
                        for (int ox = ox0; ox <= ox1; ++ox) {
                            float wx = w1d(x, ox, WW);
                            if (wx == 0.f) continue;
                            float p = sb[oy * WW + ox];
                            float lp = fmaxf(__logf(p), -100.f);
                            float l1p = fmaxf(__logf(1.f - p), -100.f);
                            contrib += wy * wx * (lp - l1p);
                        }
                    }
                }
            }
        }
    }
#pragma unroll
    for (int off = 32; off; off >>= 1) contrib += __shfl_down(contrib, off);
    __shared__ float wsum[4];
    if ((threadIdx.x & 63) == 0) wsum[wid] = contrib;
    __syncthreads();
    if (threadIdx.x == 0)
        partialC[b] = wsum[0] + wsum[1] + wsum[2] + wsum[3];
}

// 4) streaming loss (A = sum -log1mp, B = sum p*exp(-lap)) + last-block reduce
__global__ __launch_bounds__(256) void k_loss(const float* __restrict__ scores,
                                              float* __restrict__ partial,
                                              int* __restrict__ lcnt,
                                              float* __restrict__ out) {
    __shared__ float st[8][520];
    __shared__ float h5[8][512];
    int bid = blockIdx.x;
    int b = bid >> 7;
    int y0 = (bid & 127) * 4;
    const float* sb = scores + (size_t)b * HWP;
    int tid = threadIdx.x;
    int r0 = tid >> 6, c0 = tid & 63;
    for (int rr = r0; rr < 8; rr += 4) {
        int gy = reflect_idx(y0 - 2 + rr, HH);
        const float* src = sb + (size_t)gy * WW;
#pragma unroll
        for (int j = 0; j < 9; ++j) {
            int c = c0 + j * 64;
            if (c < 516) {
                int gx = c - 2;
                gx = (gx < 0) ? -gx : gx;
                gx = (gx > WW - 1) ? 2 * WW - 2 - gx : gx;
                st[rr][c] = src[gx];
            }
        }
    }
    __syncthreads();
#pragma unroll
    for (int k = 0; k < 16; ++k) {
        int idx = tid + k * 256;
        int i = idx >> 9, x = idx & 511;
        h5[i][x] = st[i][x] + st[i][x + 1] + st[i][x + 2] + st[i][x + 3] + st[i][x + 4];
    }
    __syncthreads();
    float a_loc = 0.f, b_loc = 0.f;
#pragma unroll
    for (int k = 0; k < 8; ++k) {
        int idx = tid + k * 256;
        int r = idx >> 9, x = idx & 511;
        float p = st[r + 2][x + 2];
        float s25 = h5[r][x] + h5[r + 1][x] + h5[r + 2][x] + h5[r + 3][x] + h5[r + 4][x];
        float l1p = fmaxf(__logf(1.f - p), -100.f);
        a_loc -= l1p;
        b_loc += p * __expf((25.f * p - s25) * (1.0f / 48.0f));
    }
#pragma unroll
    for (int off = 32; off; off >>= 1) {
        a_loc += __shfl_down(a_loc, off);
        b_loc += __shfl_down(b_loc, off);
    }
    __shared__ float wa[4], wbs[4];
    __shared__ bool islast;
    int wid = tid >> 6;
    if ((tid & 63) == 0) { wa[wid] = a_loc; wbs[wid] = b_loc; }
    __syncthreads();
    if (tid == 0) {
        partial[bid] = wa[0] + wa[1] + wa[2] + wa[3];
        partial[NBL + bid] = wbs[0] + wbs[1] + wbs[2] + wbs[3];
        __threadfence();
        int old = atomicAdd(lcnt, 1);
        islast = (old == NBL - 1);
    }
    __syncthreads();
    if (islast) {
        __threadfence();
        float ta = 0.f, tb = 0.f, tc = 0.f;
        for (int i = tid; i < NBL; i += 256) {
            ta += partial[i];
            tb += partial[NBL + i];
        }
        if (tid < BB) tc = partial[2 * NBL + tid];
#pragma unroll
        for (int off = 32; off; off >>= 1) {
            ta += __shfl_down(ta, off);
            tb += __shfl_down(tb, off);
            tc += __shfl_down(tc, off);
        }
        __shared__ float fa[4], fb[4], fc[4];
        if ((tid & 63) == 0) { fa[wid] = ta; fb[wid] = tb; fc[wid] = tc; }
        __syncthreads();
        if (tid == 0) {
            float A = fa[0] + fa[1] + fa[2] + fa[3];
            float Bv = fb[0] + fb[1] + fb[2] + fb[3];
            float C = fc[0] + fc[1] + fc[2] + fc[3];
            float invN = 1.0f / (float)NPIX;
            out[0] = (A - C) * invN + 10.0f * Bv * invN;
        }
    }
}

extern "C" void kernel_launch(void* const* d_in, const int* in_sizes, int n_in,
                              void* d_out, int out_size, void* d_ws, size_t ws_size,
                              hipStream_t stream) {
    const float* scores = (const float*)d_in[0];
    const float* imgs   = (const float*)d_in[1];
    float* out = (float*)d_out;

    float* ws = (float*)d_ws;
    float* S = ws;                                     // [NPIX]
    float* sval = ws + (size_t)NPIX;                   // [BB][NKEY]
    int*   sidx = (int*)(sval + (size_t)BB * NKEY);
    int*   ocnt = (int*)(sidx + (size_t)BB * NKEY);    // [BB]
    int*   lcnt = ocnt + BB;                           // [1]
    float* partial = (float*)(lcnt + 1);               // [2*NBL + BB]

    hipMemsetAsync(ocnt, 0, (BB + 1) * sizeof(int), stream);

    k_front<<<dim3(8, 32, BB), 256, 0, stream>>>(imgs, S);

    dim3 gcand(16, 64, BB);
    k_cand2<<<gcand, 256, 0, stream>>>(S, sval, sidx, ocnt);

    k_selpost<<<BB, 256, 0, stream>>>(sval, sidx, ocnt, scores, partial + 2 * NBL);

    k_loss<<<NBL, 256, 0, stream>>>(scores, partial, lcnt, out);
}

// Round 10
// 323.595 us; speedup vs baseline: 1.6606x; 1.6606x over previous
//
#include <hip/hip_runtime.h>
#include <math.h>

#define BB 16
#define HH 512
#define WW 512
#define HWP (HH*WW)
#define NPIX (BB*HWP)
#define NCORN 500
#define NSLOT 4096       // 64x64 tiles of 8x8 per image
#define OCAP 1024        // overflow for exact ties with block max (rare)
#define NKEY (NSLOT+OCAP)
#define NKPT (NKEY/256)  // keys per thread in k_sel = 20
#define NBL 2048         // k_loss blocks
#define NPOSTB 320       // k_post blocks = BB*NKEY/256

// k_front LDS float offsets (flat buffer, overlap-reused; 9304 floats = 37.2KB)
#define GTo 0            // gray 24x72 [A..B]; reused as HA 22x64 [C..D]
#define PAo 1736         // products 22x72 (+8 pad above GT to avoid halo race)
#define PCo 3320
#define PDo 4904         // end 6488
#define HAo 0
#define HCo 6488
#define HDo 7896         // end 9304
#define FBUF 9304

__device__ __constant__ float G7c[7] = {
    0.0044330482f, 0.0540055826f, 0.2420362294f, 0.3990502793f,
    0.2420362294f, 0.0540055826f, 0.0044330482f};

__device__ __forceinline__ int reflect_idx(int i, int n) {
    if (i < 0) i = -i;
    if (i >= n) i = 2 * n - 2 - i;
    return i;
}

__device__ __forceinline__ float w1d(int p, int o, int n) {
    float w = 0.f;
    int d = p - o;
    if (d >= -3 && d <= 3) w += G7c[d + 3];
    if (p >= 1 && p + o <= 3) w += G7c[3 - p - o];
    if (p <= n - 2 && p + o >= 2 * n - 5) w += G7c[2 * n + 1 - p - o];
    return w;
}

// 1) fused gray + sobel(replicate) + H/V 7-tap gaussian + min-eig -> S
//    float4 LDS pipeline; 64x16 outputs per 256-thread block.
__global__ __launch_bounds__(256) void k_front(const float* __restrict__ imgs,
                                               float* __restrict__ S) {
    __shared__ float B[FBUF];
    int x0 = blockIdx.x * 64, y0 = blockIdx.y * 16, b = blockIdx.z;
    const float* ib = imgs + (size_t)b * 3 * HWP;
    int tid = threadIdx.x;
    int r16 = tid >> 4, q16 = tid & 15;
    bool ex = (x0 == 0) || (x0 == WW - 64);

    // A: gray 24 rows x 18 quads (cols x0-4 .. x0+67)
    if (!ex) {
        for (int r = r16; r < 24; r += 16) {
            int gy = min(max(y0 - 4 + r, 0), HH - 1);
            const float* rp = ib + (size_t)gy * WW + (x0 - 4);
            for (int q = q16; q < 18; q += 16) {
                float4 R = *(const float4*)(rp + q * 4);
                float4 G = *(const float4*)(rp + HWP + q * 4);
                float4 Bl = *(const float4*)(rp + 2 * HWP + q * 4);
                float4 o;
                o.x = 0.299f*R.x + 0.587f*G.x + 0.114f*Bl.x;
                o.y = 0.299f*R.y + 0.587f*G.y + 0.114f*Bl.y;
                o.z = 0.299f*R.z + 0.587f*G.z + 0.114f*Bl.z;
                o.w = 0.299f*R.w + 0.587f*G.w + 0.114f*Bl.w;
                *(float4*)&B[GTo + r * 72 + q * 4] = o;
            }
        }
    } else {
        for (int r = r16; r < 24; r += 16) {
            int gy = min(max(y0 - 4 + r, 0), HH - 1);
            const float* rp = ib + (size_t)gy * WW;
            for (int q = q16; q < 18; q += 16) {
                float vv[4];
#pragma unroll
                for (int kk = 0; kk < 4; ++kk) {
                    int gx = min(max(x0 - 4 + q * 4 + kk, 0), WW - 1);
                    vv[kk] = 0.299f*rp[gx] + 0.587f*rp[HWP+gx] + 0.114f*rp[2*HWP+gx];
                }
                *(float4*)&B[GTo + r * 72 + q * 4] = make_float4(vv[0],vv[1],vv[2],vv[3]);
            }
        }
    }
    __syncthreads();

    // B: sobel products 22 rows x 18 quads (local cols 70,71 garbage, never read)
    for (int r = r16; r < 22; r += 16) {
        for (int q = q16; q < 18; q += 16) {
            int gb = GTo + r * 72 + q * 4;
            float4 a0 = *(const float4*)&B[gb];
            float4 a1 = *(const float4*)&B[gb + 4];
            float4 b0 = *(const float4*)&B[gb + 72];
            float4 b1 = *(const float4*)&B[gb + 76];
            float4 c0 = *(const float4*)&B[gb + 144];
            float4 c1 = *(const float4*)&B[gb + 148];
            float t0[8] = {a0.x,a0.y,a0.z,a0.w,a1.x,a1.y,a1.z,a1.w};
            float t1[8] = {b0.x,b0.y,b0.z,b0.w,b1.x,b1.y,b1.z,b1.w};
            float t2[8] = {c0.x,c0.y,c0.z,c0.w,c1.x,c1.y,c1.z,c1.w};
            float4 oA, oC, oD;
            float* pA_=(float*)&oA; float* pC_=(float*)&oC; float* pD_=(float*)&oD;
#pragma unroll
            for (int kk = 0; kk < 4; ++kk) {
                float dx = (t0[kk+2]-t0[kk] + 2.f*(t1[kk+2]-t1[kk]) + t2[kk+2]-t2[kk]) * 0.125f;
                float dy = (t2[kk]-t0[kk] + 2.f*(t2[kk+1]-t0[kk+1]) + t2[kk+2]-t0[kk+2]) * 0.125f;
                pA_[kk] = dx*dx; pC_[kk] = dy*dy; pD_[kk] = dx*dy;
            }
            int po = r * 72 + q * 4;
            *(float4*)&B[PAo + po] = oA;
            *(float4*)&B[PCo + po] = oC;
            *(float4*)&B[PDo + po] = oD;
        }
    }
    __syncthreads();

    // C: horizontal 7-tap blur -> 22 rows x 16 quads (HA overwrites dead GT)
    for (int r = r16; r < 22; r += 16) {
        int q = q16;
        bool eq = (x0 == 0 && q == 0) || (x0 == WW - 64 && q == 15);
        float4 oA, oC, oD;
        float* pA_=(float*)&oA; float* pC_=(float*)&oC; float* pD_=(float*)&oD;
        if (!eq) {
            int base = r * 72 + q * 4;
            float4 A4a = *(const float4*)&B[PAo+base], A4b = *(const float4*)&B[PAo+base+4], A4c = *(const float4*)&B[PAo+base+8];
            float4 C4a = *(const float4*)&B[PCo+base], C4b = *(const float4*)&B[PCo+base+4], C4c = *(const float4*)&B[PCo+base+8];
            float4 D4a = *(const float4*)&B[PDo+base], D4b = *(const float4*)&B[PDo+base+4], D4c = *(const float4*)&B[PDo+base+8];
            float A0[12] = {A4a.x,A4a.y,A4a.z,A4a.w,A4b.x,A4b.y,A4b.z,A4b.w,A4c.x,A4c.y,A4c.z,A4c.w};
            float C0[12] = {C4a.x,C4a.y,C4a.z,C4a.w,C4b.x,C4b.y,C4b.z,C4b.w,C4c.x,C4c.y,C4c.z,C4c.w};
            float D0[12] = {D4a.x,D4a.y,D4a.z,D4a.w,D4b.x,D4b.y,D4b.z,D4b.w,D4c.x,D4c.y,D4c.z,D4c.w};
#pragma unroll
            for (int kk = 0; kk < 4; ++kk) {
                float A = 0.f, C = 0.f, D = 0.f;
#pragma unroll
                for (int t = 0; t < 7; ++t) {
                    float w = G7c[t];
                    A += w * A0[kk+t]; C += w * C0[kk+t]; D += w * D0[kk+t];
                }
                pA_[kk] = A; pC_[kk] = C; pD_[kk] = D;
            }
        } else {
#pragma unroll
            for (int kk = 0; kk < 4; ++kk) {
                int c = q * 4 + kk;
                float A = 0.f, C = 0.f, D = 0.f;
#pragma unroll
                for (int t = 0; t < 7; ++t) {
                    int px = reflect_idx(x0 + c - 3 + t, WW);
                    int lc = r * 72 + (px - (x0 - 3));
                    float w = G7c[t];
                    A += w * B[PAo + lc]; C += w * B[PCo + lc]; D += w * B[PDo + lc];
                }
                pA_[kk] = A; pC_[kk] = C; pD_[kk] = D;
            }
        }
        int ho = r * 64 + q * 4;
        *(float4*)&B[HAo + ho] = oA;
        *(float4*)&B[HCo + ho] = oC;
        *(float4*)&B[HDo + ho] = oD;
    }
    __syncthreads();

    // D: vertical 7-tap blur + min-eig -> S (16x16 quads, 1/thread; y-reflect is per-row so f4 stays)
    {
        int r = r16, q = q16;
        int oy = y0 + r;
        bool ey = (y0 == 0) || (y0 == HH - 16);
        float4 A = {0,0,0,0}, C = {0,0,0,0}, D = {0,0,0,0};
#pragma unroll
        for (int t = 0; t < 7; ++t) {
            int lr = ey ? (reflect_idx(oy - 3 + t, HH) - (y0 - 3)) : (r + t);
            int lo = lr * 64 + q * 4;
            float w = G7c[t];
            float4 a = *(const float4*)&B[HAo + lo];
            float4 c = *(const float4*)&B[HCo + lo];
            float4 d = *(const float4*)&B[HDo + lo];
            A.x += w*a.x; A.y += w*a.y; A.z += w*a.z; A.w += w*a.w;
            C.x += w*c.x; C.y += w*c.y; C.z += w*c.z; C.w += w*c.w;
            D.x += w*d.x; D.y += w*d.y; D.z += w*d.z; D.w += w*d.w;
        }
        float4 o;
        float* pa=(float*)&A; float* pc=(float*)&C; float* pd=(float*)&D; float* po=(float*)&o;
#pragma unroll
        for (int kk = 0; kk < 4; ++kk) {
            float det = pa[kk]*pc[kk] - pd[kk]*pd[kk];
            float tr = pa[kk] + pc[kk];
            po[kk] = 0.5f * (tr - sqrtf(fabsf(tr*tr - 4.f*det)));
        }
        *(float4*)(S + (size_t)b * HWP + (size_t)oy * WW + x0 + q * 4) = o;
    }
}

// 2) per-wave 12x12 S tile (stride-16 LDS) -> 5x5 NMS + 8x8-tile max -> slot
__global__ void k_cand2(const float* __restrict__ S, float* __restrict__ sval,
                        int* __restrict__ sidx, int* __restrict__ ocnt) {
    __shared__ float tile[4][12][16];
    int wave = threadIdx.x >> 6, lane = threadIdx.x & 63;
    int tx = blockIdx.x * 4 + wave;
    int ty = blockIdx.y;
    int b = blockIdx.z;
    const float* sb = S + (size_t)b * HWP;
#pragma unroll
    for (int t = 0; t < 3; ++t) {
        int e = lane + t * 64;
        int r = e >> 4, c = e & 15;
        if (c < 12) {
            int yy = min(max(ty * 8 - 2 + r, 0), HH - 1);
            int xx = min(max(tx * 8 - 2 + c, 0), WW - 1);
            tile[wave][r][c] = sb[yy * WW + xx];
        }
    }
    __syncthreads();
    int ly = lane >> 3, lx = lane & 7;
    float v = tile[wave][ly + 2][lx + 2];
    float m = -INFINITY;
#pragma unroll
    for (int dy = 0; dy < 5; ++dy)
#pragma unroll
        for (int dx = 0; dx < 5; ++dx)
            m = fmaxf(m, tile[wave][ly + dy][lx + dx]);
    float cval = (v == m) ? v : 0.f;
    int y = ty * 8 + ly, x = tx * 8 + lx;
    float tm = cval;
#pragma unroll
    for (int off = 32; off; off >>= 1)
        tm = fmaxf(tm, __shfl_xor(tm, off));
    unsigned long long mask = __ballot(cval == tm && cval > 0.f);
    int slot = ty * 64 + tx;
    if (mask) {
        int first = __ffsll(mask) - 1;
        if (lane == first) {
            sval[b * NKEY + slot] = cval;
            sidx[b * NKEY + slot] = y * WW + x;
        } else if ((mask >> lane) & 1ull) {
            int pos = atomicAdd(&ocnt[b], 1);
            if (pos < OCAP) {
                sval[b * NKEY + NSLOT + pos] = cval;
                sidx[b * NKEY + NSLOT + pos] = y * WW + x;
            }
        }
    } else if (lane == 0) {
        sval[b * NKEY + slot] = 0.f;
        sidx[b * NKEY + slot] = 0;
    }
}

// 3) exact 500th-largest 64-bit key via 16-round nibble radix-descent.
//    Keys in registers; per-thread bins (static unroll); packed u16x2 reduce.
__global__ __launch_bounds__(256) void k_sel(const float* __restrict__ sval,
                       const int* __restrict__ sidx, const int* __restrict__ ocnt,
                       unsigned long long* __restrict__ selK) {
    __shared__ unsigned int shp[4][8];
    __shared__ int shw[4];
    __shared__ int shtot;
    int b = blockIdx.x;
    int n = NSLOT + min(ocnt[b], OCAP);
    unsigned long long keys[NKPT];
    int cnt = 0;
#pragma unroll
    for (int t = 0; t < NKPT; ++t) {
        int i = threadIdx.x + t * 256;
        unsigned long long k = 0ull;
        if (i < n) {
            float v = sval[b * NKEY + i];
            if (v > 0.f) {
                unsigned int ix = (unsigned int)sidx[b * NKEY + i];
                k = ((unsigned long long)__float_as_uint(v) << 32) |
                    (unsigned long long)(~ix);
                cnt++;
            }
        }
        keys[t] = k;
    }
    int wid = threadIdx.x >> 6;
    {
        int c = cnt;
#pragma unroll
        for (int off = 32; off; off >>= 1) c += __shfl_down(c, off);
        if ((threadIdx.x & 63) == 0) shw[wid] = c;
        __syncthreads();
        if (threadIdx.x == 0) shtot = shw[0] + shw[1] + shw[2] + shw[3];
        __syncthreads();
    }
    int target = min(NCORN, shtot);
    unsigned long long prefix = 0ull;
    int remaining = target;
    for (int shift = 60; shift >= 0; shift -= 4) {
        unsigned long long m = (shift == 60) ? 0ull : (~0ull << (shift + 4));
        unsigned int pk0=0,pk1=0,pk2=0,pk3=0,pk4=0,pk5=0,pk6=0,pk7=0;
#pragma unroll
        for (int t = 0; t < NKPT; ++t) {
            unsigned long long k = keys[t];
            bool match = (k != 0ull) && (((k ^ prefix) & m) == 0ull);
            unsigned int nib = (unsigned int)(k >> shift) & 15u;
            pk0 += (match && nib == 0u)  ? 1u : 0u;  pk0 += (match && nib == 1u)  ? 0x10000u : 0u;
            pk1 += (match && nib == 2u)  ? 1u : 0u;  pk1 += (match && nib == 3u)  ? 0x10000u : 0u;
            pk2 += (match && nib == 4u)  ? 1u : 0u;  pk2 += (match && nib == 5u)  ? 0x10000u : 0u;
            pk3 += (match && nib == 6u)  ? 1u : 0u;  pk3 += (match && nib == 7u)  ? 0x10000u : 0u;
            pk4 += (match && nib == 8u)  ? 1u : 0u;  pk4 += (match && nib == 9u)  ? 0x10000u : 0u;
            pk5 += (match && nib == 10u) ? 1u : 0u;  pk5 += (match && nib == 11u) ? 0x10000u : 0u;
            pk6 += (match && nib == 12u) ? 1u : 0u;  pk6 += (match && nib == 13u) ? 0x10000u : 0u;
            pk7 += (match && nib == 14u) ? 1u : 0u;  pk7 += (match && nib == 15u) ? 0x10000u : 0u;
        }
#pragma unroll
        for (int off = 32; off; off >>= 1) {
            pk0 += __shfl_down(pk0, off); pk1 += __shfl_down(pk1, off);
            pk2 += __shfl_down(pk2, off); pk3 += __shfl_down(pk3, off);
            pk4 += __shfl_down(pk4, off); pk5 += __shfl_down(pk5, off);
            pk6 += __shfl_down(pk6, off); pk7 += __shfl_down(pk7, off);
        }
        __syncthreads();
        if ((threadIdx.x & 63) == 0) {
            shp[wid][0]=pk0; shp[wid][1]=pk1; shp[wid][2]=pk2; shp[wid][3]=pk3;
            shp[wid][4]=pk4; shp[wid][5]=pk5; shp[wid][6]=pk6; shp[wid][7]=pk7;
        }
        __syncthreads();
        int bins[16];
#pragma unroll
        for (int j = 0; j < 8; ++j) {
            unsigned int s = shp[0][j] + shp[1][j] + shp[2][j] + shp[3][j];
            bins[2*j] = (int)(s & 0xffffu);
            bins[2*j+1] = (int)(s >> 16);
        }
        int rem = remaining, chosen = 0;
        bool done = false;
#pragma unroll
        for (int d = 15; d >= 1; --d) {
            if (!done) {
                int c = bins[d];
                if (rem - c <= 0) { chosen = d; done = true; }
                else rem -= c;
            }
        }
        prefix |= ((unsigned long long)(unsigned int)chosen) << shift;
        remaining = rem;
    }
    if (threadIdx.x == 0) selK[b] = (target > 0) ? prefix : ~0ull;
}

// 4) sparse second NMS + BCE correction C = sum_sel w*(logp - log1mp)
__global__ __launch_bounds__(256) void k_post(const float* __restrict__ sval,
                       const int* __restrict__ sidx, const int* __restrict__ ocnt,
                       const unsigned long long* __restrict__ selK,
                       const float* __restrict__ scores,
                       float* __restrict__ partialC) {
    int gid = blockIdx.x * 256 + threadIdx.x;
    int b = gid / NKEY, s = gid - b * NKEY;
    int novf = min(ocnt[b], OCAP);
    float contrib = 0.f;
    float v = (s < NSLOT + novf) ? sval[gid] : 0.f;
    if (v > 0.f) {
        unsigned int ix = (unsigned int)sidx[gid];
        unsigned long long K = selK[b];
        unsigned long long k = ((unsigned long long)__float_as_uint(v) << 32) |
                               (unsigned long long)(~ix);
        if (k >= K) {
            int y = (int)(ix >> 9), x = (int)(ix & 511);
            const float* bsv = sval + b * NKEY;
            const int* bsi = sidx + b * NKEY;
            bool sup = false;
            int ty0 = max(y - 2, 0) >> 3, ty1 = min(y + 2, HH - 1) >> 3;
            int tx0 = max(x - 2, 0) >> 3, tx1 = min(x + 2, HH - 1) >> 3;
            for (int ty = ty0; ty <= ty1 && !sup; ++ty)
                for (int tx = tx0; tx <= tx1 && !sup; ++tx) {
                    int s2 = ty * 64 + tx;
                    float v2 = bsv[s2];
                    if (v2 <= v) continue;
                    int ix2 = bsi[s2];
                    unsigned long long k2 = ((unsigned long long)__float_as_uint(v2) << 32) |
                                            (unsigned long long)(~(unsigned int)ix2);
                    if (k2 < K) continue;
                    int y2 = ix2 >> 9, x2 = ix2 & 511;
                    if (abs(y2 - y) <= 2 && abs(x2 - x) <= 2) sup = true;
                }
            for (int j = 0; j < novf && !sup; ++j) {
                float v2 = bsv[NSLOT + j];
                if (v2 <= v) continue;
                int ix2 = bsi[NSLOT + j];
                unsigned long long k2 = ((unsigned long long)__float_as_uint(v2) << 32) |
                                        (unsigned long long)(~(unsigned int)ix2);
                if (k2 < K) continue;
                int y2 = ix2 >> 9, x2 = ix2 & 511;
                if (abs(y2 - y) <= 2 && abs(x2 - x) <= 2) sup = true;
            }
            if (!sup) {
                const float* sb = scores + (size_t)b * HWP;
                if (y >= 3 && y <= HH - 4 && x >= 3 && x <= WW - 4) {
#pragma unroll
                    for (int j = -3; j <= 3; ++j) {
                        float wy = G7c[j + 3];
#pragma unroll
                        for (int i = -3; i <= 3; ++i) {
                            float w = wy * G7c[i + 3];
                            float p = sb[(y + j) * WW + (x + i)];
                            float lp = fmaxf(__logf(p), -100.f);
                            float l1p = fmaxf(__logf(1.f - p), -100.f);
                            contrib += w * (lp - l1p);
                        }
                    }
                } else {
                    int oy0 = max(y - 6, 0), oy1 = min(y + 6, HH - 1);
                    int ox0 = max(x - 6, 0), ox1 = min(x + 6, WW - 1);
                    for (int oy = oy0; oy <= oy1; ++oy) {
                        float wy = w1d(y, oy, HH);
                        if (wy == 0.f) continue;
                        for (int ox = ox0; ox <= ox1; ++ox) {
                            float wx = w1d(x, ox, WW);
                            if (wx == 0.f) continue;
                            float p = sb[oy * WW + ox];
                            float lp = fmaxf(__logf(p), -100.f);
                            float l1p = fmaxf(__logf(1.f - p), -100.f);
                            contrib += wy * wx * (lp - l1p);
                        }
                    }
                }
            }
        }
    }
#pragma unroll
    for (int off = 32; off; off >>= 1) contrib += __shfl_down(contrib, off);
    __shared__ float wsum[4];
    int wid = threadIdx.x >> 6;
    if ((threadIdx.x & 63) == 0) wsum[wid] = contrib;
    __syncthreads();
    if (threadIdx.x == 0)
        partialC[blockIdx.x] = wsum[0] + wsum[1] + wsum[2] + wsum[3];
}

// 5) streaming loss (A = sum -log1mp, B = sum p*exp(-lap)) + last-block reduce
__global__ __launch_bounds__(256) void k_loss(const float* __restrict__ scores,
                                              float* __restrict__ partial,
                                              int* __restrict__ lcnt,
                                              float* __restrict__ out) {
    __shared__ float st[8][520];
    __shared__ float h5[8][512];
    int bid = blockIdx.x;
    int b = bid >> 7;
    int y0 = (bid & 127) * 4;
    const float* sb = scores + (size_t)b * HWP;
    int tid = threadIdx.x;
    int r0 = tid >> 6, c0 = tid & 63;
    for (int rr = r0; rr < 8; rr += 4) {
        int gy = reflect_idx(y0 - 2 + rr, HH);
        const float* src = sb + (size_t)gy * WW;
#pragma unroll
        for (int j = 0; j < 9; ++j) {
            int c = c0 + j * 64;
            if (c < 516) {
                int gx = c - 2;
                gx = (gx < 0) ? -gx : gx;
                gx = (gx > WW - 1) ? 2 * WW - 2 - gx : gx;
                st[rr][c] = src[gx];
            }
        }
    }
    __syncthreads();
#pragma unroll
    for (int k = 0; k < 16; ++k) {
        int idx = tid + k * 256;
        int i = idx >> 9, x = idx & 511;
        h5[i][x] = st[i][x] + st[i][x + 1] + st[i][x + 2] + st[i][x + 3] + st[i][x + 4];
    }
    __syncthreads();
    float a_loc = 0.f, b_loc = 0.f;
#pragma unroll
    for (int k = 0; k < 8; ++k) {
        int idx = tid + k * 256;
        int r = idx >> 9, x = idx & 511;
        float p = st[r + 2][x + 2];
        float s25 = h5[r][x] + h5[r + 1][x] + h5[r + 2][x] + h5[r + 3][x] + h5[r + 4][x];
        float l1p = fmaxf(__logf(1.f - p), -100.f);
        a_loc -= l1p;
        b_loc += p * __expf((25.f * p - s25) * (1.0f / 48.0f));
    }
#pragma unroll
    for (int off = 32; off; off >>= 1) {
        a_loc += __shfl_down(a_loc, off);
        b_loc += __shfl_down(b_loc, off);
    }
    __shared__ float wa[4], wbs[4];
    __shared__ bool islast;
    int wid = tid >> 6;
    if ((tid & 63) == 0) { wa[wid] = a_loc; wbs[wid] = b_loc; }
    __syncthreads();
    if (tid == 0) {
        partial[bid] = wa[0] + wa[1] + wa[2] + wa[3];
        partial[NBL + bid] = wbs[0] + wbs[1] + wbs[2] + wbs[3];
        __threadfence();
        int old = atomicAdd(lcnt, 1);
        islast = (old == NBL - 1);
    }
    __syncthreads();
    if (islast) {
        __threadfence();
        float ta = 0.f, tb = 0.f, tc = 0.f;
        for (int i = tid; i < NBL; i += 256) {
            ta += partial[i];
            tb += partial[NBL + i];
        }
        for (int i = tid; i < NPOSTB; i += 256)
            tc += partial[2 * NBL + i];
#pragma unroll
        for (int off = 32; off; off >>= 1) {
            ta += __shfl_down(ta, off);
            tb += __shfl_down(tb, off);
            tc += __shfl_down(tc, off);
        }
        __shared__ float fa[4], fb[4], fc[4];
        if ((tid & 63) == 0) { fa[wid] = ta; fb[wid] = tb; fc[wid] = tc; }
        __syncthreads();
        if (tid == 0) {
            float A = fa[0] + fa[1] + fa[2] + fa[3];
            float Bv = fb[0] + fb[1] + fb[2] + fb[3];
            float C = fc[0] + fc[1] + fc[2] + fc[3];
            float invN = 1.0f / (float)NPIX;
            out[0] = (A - C) * invN + 10.0f * Bv * invN;
        }
    }
}

extern "C" void kernel_launch(void* const* d_in, const int* in_sizes, int n_in,
                              void* d_out, int out_size, void* d_ws, size_t ws_size,
                              hipStream_t stream) {
    const float* scores = (const float*)d_in[0];
    const float* imgs   = (const float*)d_in[1];
    float* out = (float*)d_out;

    float* ws = (float*)d_ws;
    float* S = ws;                                     // [NPIX]
    float* sval = ws + (size_t)NPIX;                   // [BB][NKEY]
    int*   sidx = (int*)(sval + (size_t)BB * NKEY);
    int*   ocnt = (int*)(sidx + (size_t)BB * NKEY);    // [BB]
    int*   lcnt = ocnt + BB;                           // [1]
    unsigned long long* selK = (unsigned long long*)(lcnt + 1);  // [BB] (8B-aligned: offset even)
    float* partial = (float*)(selK + BB);              // [2*NBL + NPOSTB]

    hipMemsetAsync(ocnt, 0, (BB + 1) * sizeof(int), stream);

    k_front<<<dim3(8, 32, BB), 256, 0, stream>>>(imgs, S);

    dim3 gcand(16, 64, BB);
    k_cand2<<<gcand, 256, 0, stream>>>(S, sval, sidx, ocnt);

    k_sel<<<BB, 256, 0, stream>>>(sval, sidx, ocnt, selK);
    k_post<<<NPOSTB, 256, 0, stream>>>(sval, sidx, ocnt, selK, scores,
                                       partial + 2 * NBL);

    k_loss<<<NBL, 256, 0, stream>>>(scores, partial, lcnt, out);
}

// Round 11
// 282.509 us; speedup vs baseline: 1.9021x; 1.1454x over previous
//
#include <hip/hip_runtime.h>
#include <math.h>

#define BB 16
#define HH 512
#define WW 512
#define HWP (HH*WW)
#define NPIX (BB*HWP)
#define NCORN 500
#define NSLOT 4096       // 64x64 tiles of 8x8 per image
#define OCAP 1024        // overflow for exact ties with block max (rare)
#define NKEY (NSLOT+OCAP)
#define NKPT (NKEY/256)  // keys per thread in k_sel = 20
#define NBL 2048         // k_loss blocks
#define NPOSTB 320       // k_post blocks = BB*NKEY/256

// k_front LDS float offsets (flat buffer, overlap-reused; 9304 floats = 37.2KB)
#define GTo 0            // gray 24x72 [A..B]; reused as HA 22x64 [C..D]
#define PAo 1736         // products 22x72 (+8 pad above GT to avoid halo race)
#define PCo 3320
#define PDo 4904         // end 6488
#define HAo 0
#define HCo 6488
#define HDo 7896         // end 9304
#define FBUF 9304

__device__ __constant__ float G7c[7] = {
    0.0044330482f, 0.0540055826f, 0.2420362294f, 0.3990502793f,
    0.2420362294f, 0.0540055826f, 0.0044330482f};

__device__ __forceinline__ int reflect_idx(int i, int n) {
    if (i < 0) i = -i;
    if (i >= n) i = 2 * n - 2 - i;
    return i;
}

__device__ __forceinline__ float w1d(int p, int o, int n) {
    float w = 0.f;
    int d = p - o;
    if (d >= -3 && d <= 3) w += G7c[d + 3];
    if (p >= 1 && p + o <= 3) w += G7c[3 - p - o];
    if (p <= n - 2 && p + o >= 2 * n - 5) w += G7c[2 * n + 1 - p - o];
    return w;
}

// 1) fused gray + sobel(replicate) + H/V 7-tap gaussian + min-eig -> S
__global__ __launch_bounds__(256) void k_front(const float* __restrict__ imgs,
                                               float* __restrict__ S) {
    __shared__ float B[FBUF];
    int x0 = blockIdx.x * 64, y0 = blockIdx.y * 16, b = blockIdx.z;
    const float* ib = imgs + (size_t)b * 3 * HWP;
    int tid = threadIdx.x;
    int r16 = tid >> 4, q16 = tid & 15;
    bool ex = (x0 == 0) || (x0 == WW - 64);

    // A: gray 24 rows x 18 quads (cols x0-4 .. x0+67)
    if (!ex) {
        for (int r = r16; r < 24; r += 16) {
            int gy = min(max(y0 - 4 + r, 0), HH - 1);
            const float* rp = ib + (size_t)gy * WW + (x0 - 4);
            for (int q = q16; q < 18; q += 16) {
                float4 R = *(const float4*)(rp + q * 4);
                float4 G = *(const float4*)(rp + HWP + q * 4);
                float4 Bl = *(const float4*)(rp + 2 * HWP + q * 4);
                float4 o;
                o.x = 0.299f*R.x + 0.587f*G.x + 0.114f*Bl.x;
                o.y = 0.299f*R.y + 0.587f*G.y + 0.114f*Bl.y;
                o.z = 0.299f*R.z + 0.587f*G.z + 0.114f*Bl.z;
                o.w = 0.299f*R.w + 0.587f*G.w + 0.114f*Bl.w;
                *(float4*)&B[GTo + r * 72 + q * 4] = o;
            }
        }
    } else {
        for (int r = r16; r < 24; r += 16) {
            int gy = min(max(y0 - 4 + r, 0), HH - 1);
            const float* rp = ib + (size_t)gy * WW;
            for (int q = q16; q < 18; q += 16) {
                float vv[4];
#pragma unroll
                for (int kk = 0; kk < 4; ++kk) {
                    int gx = min(max(x0 - 4 + q * 4 + kk, 0), WW - 1);
                    vv[kk] = 0.299f*rp[gx] + 0.587f*rp[HWP+gx] + 0.114f*rp[2*HWP+gx];
                }
                *(float4*)&B[GTo + r * 72 + q * 4] = make_float4(vv[0],vv[1],vv[2],vv[3]);
            }
        }
    }
    __syncthreads();

    // B: sobel products 22 rows x 18 quads
    for (int r = r16; r < 22; r += 16) {
        for (int q = q16; q < 18; q += 16) {
            int gb = GTo + r * 72 + q * 4;
            float4 a0 = *(const float4*)&B[gb];
            float4 a1 = *(const float4*)&B[gb + 4];
            float4 b0 = *(const float4*)&B[gb + 72];
            float4 b1 = *(const float4*)&B[gb + 76];
            float4 c0 = *(const float4*)&B[gb + 144];
            float4 c1 = *(const float4*)&B[gb + 148];
            float t0[8] = {a0.x,a0.y,a0.z,a0.w,a1.x,a1.y,a1.z,a1.w};
            float t1[8] = {b0.x,b0.y,b0.z,b0.w,b1.x,b1.y,b1.z,b1.w};
            float t2[8] = {c0.x,c0.y,c0.z,c0.w,c1.x,c1.y,c1.z,c1.w};
            float4 oA, oC, oD;
            float* pA_=(float*)&oA; float* pC_=(float*)&oC; float* pD_=(float*)&oD;
#pragma unroll
            for (int kk = 0; kk < 4; ++kk) {
                float dx = (t0[kk+2]-t0[kk] + 2.f*(t1[kk+2]-t1[kk]) + t2[kk+2]-t2[kk]) * 0.125f;
                float dy = (t2[kk]-t0[kk] + 2.f*(t2[kk+1]-t0[kk+1]) + t2[kk+2]-t0[kk+2]) * 0.125f;
                pA_[kk] = dx*dx; pC_[kk] = dy*dy; pD_[kk] = dx*dy;
            }
            int po = r * 72 + q * 4;
            *(float4*)&B[PAo + po] = oA;
            *(float4*)&B[PCo + po] = oC;
            *(float4*)&B[PDo + po] = oD;
        }
    }
    __syncthreads();

    // C: horizontal 7-tap blur -> 22 rows x 16 quads (HA overwrites dead GT)
    for (int r = r16; r < 22; r += 16) {
        int q = q16;
        bool eq = (x0 == 0 && q == 0) || (x0 == WW - 64 && q == 15);
        float4 oA, oC, oD;
        float* pA_=(float*)&oA; float* pC_=(float*)&oC; float* pD_=(float*)&oD;
        if (!eq) {
            int base = r * 72 + q * 4;
            float4 A4a = *(const float4*)&B[PAo+base], A4b = *(const float4*)&B[PAo+base+4], A4c = *(const float4*)&B[PAo+base+8];
            float4 C4a = *(const float4*)&B[PCo+base], C4b = *(const float4*)&B[PCo+base+4], C4c = *(const float4*)&B[PCo+base+8];
            float4 D4a = *(const float4*)&B[PDo+base], D4b = *(const float4*)&B[PDo+base+4], D4c = *(const float4*)&B[PDo+base+8];
            float A0[12] = {A4a.x,A4a.y,A4a.z,A4a.w,A4b.x,A4b.y,A4b.z,A4b.w,A4c.x,A4c.y,A4c.z,A4c.w};
            float C0[12] = {C4a.x,C4a.y,C4a.z,C4a.w,C4b.x,C4b.y,C4b.z,C4b.w,C4c.x,C4c.y,C4c.z,C4c.w};
            float D0[12] = {D4a.x,D4a.y,D4a.z,D4a.w,D4b.x,D4b.y,D4b.z,D4b.w,D4c.x,D4c.y,D4c.z,D4c.w};
#pragma unroll
            for (int kk = 0; kk < 4; ++kk) {
                float A = 0.f, C = 0.f, D = 0.f;
#pragma unroll
                for (int t = 0; t < 7; ++t) {
                    float w = G7c[t];
                    A += w * A0[kk+t]; C += w * C0[kk+t]; D += w * D0[kk+t];
                }
                pA_[kk] = A; pC_[kk] = C; pD_[kk] = D;
            }
        } else {
#pragma unroll
            for (int kk = 0; kk < 4; ++kk) {
                int c = q * 4 + kk;
                float A = 0.f, C = 0.f, D = 0.f;
#pragma unroll
                for (int t = 0; t < 7; ++t) {
                    int px = reflect_idx(x0 + c - 3 + t, WW);
                    int lc = r * 72 + (px - (x0 - 3));
                    float w = G7c[t];
                    A += w * B[PAo + lc]; C += w * B[PCo + lc]; D += w * B[PDo + lc];
                }
                pA_[kk] = A; pC_[kk] = C; pD_[kk] = D;
            }
        }
        int ho = r * 64 + q * 4;
        *(float4*)&B[HAo + ho] = oA;
        *(float4*)&B[HCo + ho] = oC;
        *(float4*)&B[HDo + ho] = oD;
    }
    __syncthreads();

    // D: vertical 7-tap blur + min-eig -> S
    {
        int r = r16, q = q16;
        int oy = y0 + r;
        bool ey = (y0 == 0) || (y0 == HH - 16);
        float4 A = {0,0,0,0}, C = {0,0,0,0}, D = {0,0,0,0};
#pragma unroll
        for (int t = 0; t < 7; ++t) {
            int lr = ey ? (reflect_idx(oy - 3 + t, HH) - (y0 - 3)) : (r + t);
            int lo = lr * 64 + q * 4;
            float w = G7c[t];
            float4 a = *(const float4*)&B[HAo + lo];
            float4 c = *(const float4*)&B[HCo + lo];
            float4 d = *(const float4*)&B[HDo + lo];
            A.x += w*a.x; A.y += w*a.y; A.z += w*a.z; A.w += w*a.w;
            C.x += w*c.x; C.y += w*c.y; C.z += w*c.z; C.w += w*c.w;
            D.x += w*d.x; D.y += w*d.y; D.z += w*d.z; D.w += w*d.w;
        }
        float4 o;
        float* pa=(float*)&A; float* pc=(float*)&C; float* pd=(float*)&D; float* po=(float*)&o;
#pragma unroll
        for (int kk = 0; kk < 4; ++kk) {
            float det = pa[kk]*pc[kk] - pd[kk]*pd[kk];
            float tr = pa[kk] + pc[kk];
            po[kk] = 0.5f * (tr - sqrtf(fabsf(tr*tr - 4.f*det)));
        }
        *(float4*)(S + (size_t)b * HWP + (size_t)oy * WW + x0 + q * 4) = o;
    }
}

// 2) per-wave 12x12 S tile (stride-16 LDS) -> 5x5 NMS + 8x8-tile max -> slot
__global__ void k_cand2(const float* __restrict__ S, float* __restrict__ sval,
                        int* __restrict__ sidx, int* __restrict__ ocnt) {
    __shared__ float tile[4][12][16];
    int wave = threadIdx.x >> 6, lane = threadIdx.x & 63;
    int tx = blockIdx.x * 4 + wave;
    int ty = blockIdx.y;
    int b = blockIdx.z;
    const float* sb = S + (size_t)b * HWP;
#pragma unroll
    for (int t = 0; t < 3; ++t) {
        int e = lane + t * 64;
        int r = e >> 4, c = e & 15;
        if (c < 12) {
            int yy = min(max(ty * 8 - 2 + r, 0), HH - 1);
            int xx = min(max(tx * 8 - 2 + c, 0), WW - 1);
            tile[wave][r][c] = sb[yy * WW + xx];
        }
    }
    __syncthreads();
    int ly = lane >> 3, lx = lane & 7;
    float v = tile[wave][ly + 2][lx + 2];
    float m = -INFINITY;
#pragma unroll
    for (int dy = 0; dy < 5; ++dy)
#pragma unroll
        for (int dx = 0; dx < 5; ++dx)
            m = fmaxf(m, tile[wave][ly + dy][lx + dx]);
    float cval = (v == m) ? v : 0.f;
    int y = ty * 8 + ly, x = tx * 8 + lx;
    float tm = cval;
#pragma unroll
    for (int off = 32; off; off >>= 1)
        tm = fmaxf(tm, __shfl_xor(tm, off));
    unsigned long long mask = __ballot(cval == tm && cval > 0.f);
    int slot = ty * 64 + tx;
    if (mask) {
        int first = __ffsll(mask) - 1;
        if (lane == first) {
            sval[b * NKEY + slot] = cval;
            sidx[b * NKEY + slot] = y * WW + x;
        } else if ((mask >> lane) & 1ull) {
            int pos = atomicAdd(&ocnt[b], 1);
            if (pos < OCAP) {
                sval[b * NKEY + NSLOT + pos] = cval;
                sidx[b * NKEY + NSLOT + pos] = y * WW + x;
            }
        }
    } else if (lane == 0) {
        sval[b * NKEY + slot] = 0.f;
        sidx[b * NKEY + slot] = 0;
    }
}

// 3) exact 500th-largest key: hi/lo split bit-descent over LDS-resident keys.
//    No register key arrays (no spill), no LDS atomics.
__global__ __launch_bounds__(256) void k_sel(const float* __restrict__ sval,
                       const int* __restrict__ sidx, const int* __restrict__ ocnt,
                       unsigned long long* __restrict__ selK) {
    __shared__ unsigned int khi[NKEY];   // 20KB
    __shared__ unsigned int klo[NKEY];   // 20KB
    __shared__ int shw[4];
    int b = blockIdx.x;
    int n = NSLOT + min(ocnt[b], OCAP);
    int tid = threadIdx.x;
    int wid = tid >> 6;
    int cnt = 0;
#pragma unroll
    for (int t = 0; t < NKPT; ++t) {
        int i = tid + t * 256;
        unsigned int h = 0u, l = 0u;
        if (i < n) {
            float v = sval[b * NKEY + i];
            if (v > 0.f) {
                h = __float_as_uint(v);
                l = ~(unsigned int)sidx[b * NKEY + i];
                cnt++;
            }
        }
        khi[i] = h; klo[i] = l;
    }
    {
        int c = cnt;
#pragma unroll
        for (int off = 32; off; off >>= 1) c += __shfl_down(c, off);
        if ((tid & 63) == 0) shw[wid] = c;
    }
    __syncthreads();
    int target = min(NCORN, shw[0] + shw[1] + shw[2] + shw[3]);

    // hi-word descent: key >= (cand<<32) <=> hi >= cand
    unsigned int Thi = 0u;
    for (int bit = 31; bit >= 0; --bit) {
        unsigned int cand = Thi | (1u << bit);
        int c = 0;
#pragma unroll
        for (int t = 0; t < NKPT; ++t)
            c += (khi[tid + t * 256] >= cand) ? 1 : 0;
#pragma unroll
        for (int off = 32; off; off >>= 1) c += __shfl_down(c, off);
        __syncthreads();                 // WAR protect shw
        if ((tid & 63) == 0) shw[wid] = c;
        __syncthreads();
        int tot = shw[0] + shw[1] + shw[2] + shw[3];
        if (tot >= target) Thi = cand;
    }
    // per-thread gt/eq masks vs Thi (zero-keys have h==0 < Thi when target>0)
    unsigned int gtm = 0u, eqm = 0u;
#pragma unroll
    for (int t = 0; t < NKPT; ++t) {
        unsigned int h = khi[tid + t * 256];
        gtm |= (h > Thi) ? (1u << t) : 0u;
        eqm |= (h == Thi) ? (1u << t) : 0u;
    }
    int base = __popc(gtm);
    // lo-word descent among hi==Thi keys
    unsigned int Tlo = 0u;
    for (int bit = 31; bit >= 0; --bit) {
        unsigned int cand = Tlo | (1u << bit);
        int c = base;
#pragma unroll
        for (int t = 0; t < NKPT; ++t)
            if ((eqm >> t) & 1u)
                c += (klo[tid + t * 256] >= cand) ? 1 : 0;
#pragma unroll
        for (int off = 32; off; off >>= 1) c += __shfl_down(c, off);
        __syncthreads();
        if ((tid & 63) == 0) shw[wid] = c;
        __syncthreads();
        int tot = shw[0] + shw[1] + shw[2] + shw[3];
        if (tot >= target) Tlo = cand;
    }
    if (tid == 0)
        selK[b] = (target > 0)
                ? (((unsigned long long)Thi << 32) | (unsigned long long)Tlo)
                : ~0ull;
}

// 4) sparse second NMS + BCE correction C = sum_sel w*(logp - log1mp)
__global__ __launch_bounds__(256) void k_post(const float* __restrict__ sval,
                       const int* __restrict__ sidx, const int* __restrict__ ocnt,
                       const unsigned long long* __restrict__ selK,
                       const float* __restrict__ scores,
                       float* __restrict__ partialC) {
    int gid = blockIdx.x * 256 + threadIdx.x;
    int b = gid / NKEY, s = gid - b * NKEY;
    int novf = min(ocnt[b], OCAP);
    float contrib = 0.f;
    float v = (s < NSLOT + novf) ? sval[gid] : 0.f;
    if (v > 0.f) {
        unsigned int ix = (unsigned int)sidx[gid];
        unsigned long long K = selK[b];
        unsigned long long k = ((unsigned long long)__float_as_uint(v) << 32) |
                               (unsigned long long)(~ix);
        if (k >= K) {
            int y = (int)(ix >> 9), x = (int)(ix & 511);
            const float* bsv = sval + b * NKEY;
            const int* bsi = sidx + b * NKEY;
            bool sup = false;
            int ty0 = max(y - 2, 0) >> 3, ty1 = min(y + 2, HH - 1) >> 3;
            int tx0 = max(x - 2, 0) >> 3, tx1 = min(x + 2, WW - 1) >> 3;
            for (int ty = ty0; ty <= ty1 && !sup; ++ty)
                for (int tx = tx0; tx <= tx1 && !sup; ++tx) {
                    int s2 = ty * 64 + tx;
                    float v2 = bsv[s2];
                    if (v2 <= v) continue;
                    int ix2 = bsi[s2];
                    unsigned long long k2 = ((unsigned long long)__float_as_uint(v2) << 32) |
                                            (unsigned long long)(~(unsigned int)ix2);
                    if (k2 < K) continue;
                    int y2 = ix2 >> 9, x2 = ix2 & 511;
                    if (abs(y2 - y) <= 2 && abs(x2 - x) <= 2) sup = true;
                }
            for (int j = 0; j < novf && !sup; ++j) {
                float v2 = bsv[NSLOT + j];
                if (v2 <= v) continue;
                int ix2 = bsi[NSLOT + j];
                unsigned long long k2 = ((unsigned long long)__float_as_uint(v2) << 32) |
                                        (unsigned long long)(~(unsigned int)ix2);
                if (k2 < K) continue;
                int y2 = ix2 >> 9, x2 = ix2 & 511;
                if (abs(y2 - y) <= 2 && abs(x2 - x) <= 2) sup = true;
            }
            if (!sup) {
                const float* sb = scores + (size_t)b * HWP;
                if (y >= 3 && y <= HH - 4 && x >= 3 && x <= WW - 4) {
#pragma unroll
                    for (int j = -3; j <= 3; ++j) {
                        float wy = G7c[j + 3];
#pragma unroll
                        for (int i = -3; i <= 3; ++i) {
                            float w = wy * G7c[i + 3];
                            float p = sb[(y + j) * WW + (x + i)];
                            float lp = fmaxf(__logf(p), -100.f);
                            float l1p = fmaxf(__logf(1.f - p), -100.f);
                            contrib += w * (lp - l1p);
                        }
                    }
                } else {
                    int oy0 = max(y - 6, 0), oy1 = min(y + 6, HH - 1);
                    int ox0 = max(x - 6, 0), ox1 = min(x + 6, WW - 1);
                    for (int oy = oy0; oy <= oy1; ++oy) {
                        float wy = w1d(y, oy, HH);
                        if (wy == 0.f) continue;
                        for (int ox = ox0; ox <= ox1; ++ox) {
                            float wx = w1d(x, ox, WW);
                            if (wx == 0.f) continue;
                            float p = sb[oy * WW + ox];
                            float lp = fmaxf(__logf(p), -100.f);
                            float l1p = fmaxf(__logf(1.f - p), -100.f);
                            contrib += wy * wx * (lp - l1p);
                        }
                    }
                }
            }
        }
    }
#pragma unroll
    for (int off = 32; off; off >>= 1) contrib += __shfl_down(contrib, off);
    __shared__ float wsum[4];
    int wid = threadIdx.x >> 6;
    if ((threadIdx.x & 63) == 0) wsum[wid] = contrib;
    __syncthreads();
    if (threadIdx.x == 0)
        partialC[blockIdx.x] = wsum[0] + wsum[1] + wsum[2] + wsum[3];
}

// 5) streaming loss (A = sum -log1mp, B = sum p*exp(-lap)) + last-block reduce
__global__ __launch_bounds__(256) void k_loss(const float* __restrict__ scores,
                                              float* __restrict__ partial,
                                              int* __restrict__ lcnt,
                                              float* __restrict__ out) {
    __shared__ float st[8][520];
    __shared__ float h5[8][512];
    int bid = blockIdx.x;
    int b = bid >> 7;
    int y0 = (bid & 127) * 4;
    const float* sb = scores + (size_t)b * HWP;
    int tid = threadIdx.x;
    int r0 = tid >> 6, c0 = tid & 63;
    for (int rr = r0; rr < 8; rr += 4) {
        int gy = reflect_idx(y0 - 2 + rr, HH);
        const float* src = sb + (size_t)gy * WW;
#pragma unroll
        for (int j = 0; j < 9; ++j) {
            int c = c0 + j * 64;
            if (c < 516) {
                int gx = c - 2;
                gx = (gx < 0) ? -gx : gx;
                gx = (gx > WW - 1) ? 2 * WW - 2 - gx : gx;
                st[rr][c] = src[gx];
            }
        }
    }
    __syncthreads();
#pragma unroll
    for (int k = 0; k < 16; ++k) {
        int idx = tid + k * 256;
        int i = idx >> 9, x = idx & 511;
        h5[i][x] = st[i][x] + st[i][x + 1] + st[i][x + 2] + st[i][x + 3] + st[i][x + 4];
    }
    __syncthreads();
    float a_loc = 0.f, b_loc = 0.f;
#pragma unroll
    for (int k = 0; k < 8; ++k) {
        int idx = tid + k * 256;
        int r = idx >> 9, x = idx & 511;
        float p = st[r + 2][x + 2];
        float s25 = h5[r][x] + h5[r + 1][x] + h5[r + 2][x] + h5[r + 3][x] + h5[r + 4][x];
        float l1p = fmaxf(__logf(1.f - p), -100.f);
        a_loc -= l1p;
        b_loc += p * __expf((25.f * p - s25) * (1.0f / 48.0f));
    }
#pragma unroll
    for (int off = 32; off; off >>= 1) {
        a_loc += __shfl_down(a_loc, off);
        b_loc += __shfl_down(b_loc, off);
    }
    __shared__ float wa[4], wbs[4];
    __shared__ bool islast;
    int wid = tid >> 6;
    if ((tid & 63) == 0) { wa[wid] = a_loc; wbs[wid] = b_loc; }
    __syncthreads();
    if (tid == 0) {
        partial[bid] = wa[0] + wa[1] + wa[2] + wa[3];
        partial[NBL + bid] = wbs[0] + wbs[1] + wbs[2] + wbs[3];
        __threadfence();
        int old = atomicAdd(lcnt, 1);
        islast = (old == NBL - 1);
    }
    __syncthreads();
    if (islast) {
        __threadfence();
        float ta = 0.f, tb = 0.f, tc = 0.f;
        for (int i = tid; i < NBL; i += 256) {
            ta += partial[i];
            tb += partial[NBL + i];
        }
        for (int i = tid; i < NPOSTB; i += 256)
            tc += partial[2 * NBL + i];
#pragma unroll
        for (int off = 32; off; off >>= 1) {
            ta += __shfl_down(ta, off);
            tb += __shfl_down(tb, off);
            tc += __shfl_down(tc, off);
        }
        __shared__ float fa[4], fb[4], fc[4];
        if ((tid & 63) == 0) { fa[wid] = ta; fb[wid] = tb; fc[wid] = tc; }
        __syncthreads();
        if (tid == 0) {
            float A = fa[0] + fa[1] + fa[2] + fa[3];
            float Bv = fb[0] + fb[1] + fb[2] + fb[3];
            float C = fc[0] + fc[1] + fc[2] + fc[3];
            float invN = 1.0f / (float)NPIX;
            out[0] = (A - C) * invN + 10.0f * Bv * invN;
        }
    }
}

extern "C" void kernel_launch(void* const* d_in, const int* in_sizes, int n_in,
                              void* d_out, int out_size, void* d_ws, size_t ws_size,
                              hipStream_t stream) {
    const float* scores = (const float*)d_in[0];
    const float* imgs   = (const float*)d_in[1];
    float* out = (float*)d_out;

    float* ws = (float*)d_ws;
    float* S = ws;                                     // [NPIX]
    float* sval = ws + (size_t)NPIX;                   // [BB][NKEY]
    int*   sidx = (int*)(sval + (size_t)BB * NKEY);
    int*   ocnt = (int*)(sidx + (size_t)BB * NKEY);    // [BB]
    int*   lcnt = ocnt + BB;                           // [1]
    unsigned long long* selK = (unsigned long long*)(lcnt + 1);  // [BB]
    float* partial = (float*)(selK + BB);              // [2*NBL + NPOSTB]

    hipMemsetAsync(ocnt, 0, (BB + 1) * sizeof(int), stream);

    k_front<<<dim3(8, 32, BB), 256, 0, stream>>>(imgs, S);

    dim3 gcand(16, 64, BB);
    k_cand2<<<gcand, 256, 0, stream>>>(S, sval, sidx, ocnt);

    k_sel<<<BB, 256, 0, stream>>>(sval, sidx, ocnt, selK);
    k_post<<<NPOSTB, 256, 0, stream>>>(sval, sidx, ocnt, selK, scores,
                                       partial + 2 * NBL);

    k_loss<<<NBL, 256, 0, stream>>>(scores, partial, lcnt, out);
}